// Round 2
// 637.476 us; speedup vs baseline: 1.0269x; 1.0269x over previous
//
#include <hip/hip_runtime.h>

// S_LSTM: T=16 timesteps, H=1024, NLAYER=4.
// All ops are elementwise over (H,H): 1M independent scalar LSTM chains,
// one thread per (r,c); weights+state live in registers across the t-loop.
//
// V2 (resubmit after infra failure; theory: latency-bound at ~20-30% of
// both rooflines):
//  - x[t] software-prefetch: the per-timestep global load no longer sits on
//    the serial dependency chain.
//  - weights pre-scaled by log2(e) (candidate gate by 2*log2(e)) so each
//    sigmoid/tanh is rcp(1+exp2(-z)) with negation folded into a modifier:
//    ~6 fewer VALU ops per layer-step and a shorter chain into each v_exp.
//  - non-temporal stores for the 512 MiB output stream; NT loads for the
//    read-once Wh/Whs weights (don't thrash 4 MiB/XCD L2).
//  - __launch_bounds__(256,4): pin >=4 waves/SIMD for latency hiding.

constexpr int T  = 16;
constexpr int H  = 1024;
constexpr int NL = 4;
constexpr int HH = H * H;

constexpr float L2E  = 1.4426950408889634f;  // log2(e)
constexpr float L2E2 = 2.8853900817779268f;  // 2*log2(e)

__device__ __forceinline__ float exp2_fast(float x) {
#if __has_builtin(__builtin_amdgcn_exp2f)
    return __builtin_amdgcn_exp2f(x);      // v_exp_f32 (2^x)
#else
    return __expf(x * 0.6931471805599453f);
#endif
}
// sigmoid(z) given z2 = z*log2(e):  1/(1 + 2^-z2)
__device__ __forceinline__ float sig_p(float z2) {
    return __builtin_amdgcn_rcpf(1.0f + exp2_fast(-z2));
}
// tanh(z) given z2 = z*2*log2(e):  2/(1 + 2^-z2) - 1
__device__ __forceinline__ float tanh_p(float z2) {
    return fmaf(2.0f, __builtin_amdgcn_rcpf(1.0f + exp2_fast(-z2)), -1.0f);
}

__global__ __launch_bounds__(256, 4)
void slstm_kernel(const float* __restrict__ x,
                  const float* __restrict__ Wxi, const float* __restrict__ Wxf,
                  const float* __restrict__ Wxc, const float* __restrict__ Wxo,
                  const float* __restrict__ Whi, const float* __restrict__ Whf,
                  const float* __restrict__ Whc, const float* __restrict__ Who,
                  const float* __restrict__ Whsi, const float* __restrict__ Whsf,
                  const float* __restrict__ Whsc, const float* __restrict__ Whso,
                  const float* __restrict__ bi, const float* __restrict__ bf,
                  const float* __restrict__ bc, const float* __restrict__ bo,
                  float* __restrict__ out)
{
    const int idx = blockIdx.x * blockDim.x + threadIdx.x;   // 0 .. HH-1
    const int r = idx >> 10;          // row    (x broadcast index)
    const int c = idx & (H - 1);      // column (Wx/b broadcast index)

    // ---- load all per-position weights into registers, pre-scaled ----
    // i/f/o-gate sets scaled by log2(e); c-gate set by 2*log2(e) (tanh arg).
    float whi[NL], whf[NL], whc[NL], who[NL];
    float wxi[NL], wxf[NL], wxc[NL], wxo[NL];
    float vbi[NL], vbf[NL], vbc[NL], vbo[NL];
#pragma unroll
    for (int i = 0; i < NL; ++i) {
        whi[i] = __builtin_nontemporal_load(&Whi[i * HH + idx]) * L2E;
        whf[i] = __builtin_nontemporal_load(&Whf[i * HH + idx]) * L2E;
        whc[i] = __builtin_nontemporal_load(&Whc[i * HH + idx]) * L2E2;
        who[i] = __builtin_nontemporal_load(&Who[i * HH + idx]) * L2E;
        wxi[i] = Wxi[i * H + c] * L2E;
        wxf[i] = Wxf[i * H + c] * L2E;
        wxc[i] = Wxc[i * H + c] * L2E2;
        wxo[i] = Wxo[i * H + c] * L2E;
        vbi[i] = bi[i * H + c] * L2E;
        vbf[i] = bf[i * H + c] * L2E;
        vbc[i] = bc[i * H + c] * L2E2;
        vbo[i] = bo[i * H + c] * L2E;
    }
    float wsi[NL - 1], wsf[NL - 1], wsc[NL - 1], wso[NL - 1];
#pragma unroll
    for (int j = 0; j < NL - 1; ++j) {
        wsi[j] = __builtin_nontemporal_load(&Whsi[j * HH + idx]) * L2E;
        wsf[j] = __builtin_nontemporal_load(&Whsf[j * HH + idx]) * L2E;
        wsc[j] = __builtin_nontemporal_load(&Whsc[j * HH + idx]) * L2E2;
        wso[j] = __builtin_nontemporal_load(&Whso[j * HH + idx]) * L2E;
    }

    float cs[NL] = {0.f, 0.f, 0.f, 0.f};
    float hs[NL] = {0.f, 0.f, 0.f, 0.f};

    float xv = x[r];                    // t = 0 value (wave-uniform)
    float* outp = out + idx;

    for (int t = 0; t < T; ++t) {
        // prefetch next timestep's x; latency hides under this iteration.
        // (t==T-1 re-reads x[t]; value unused, keeps the chain branch-free)
        const int tn = (t + 1) & (T - 1) ? (t + 1) : t;
        const float xnext = x[(t + 1 < T ? t + 1 : t) * H + r];
        (void)tn;

        float hbelow = 0.0f;
#pragma unroll
        for (int i = 0; i < NL; ++i) {
            float zi = fmaf(xv, wxi[i], fmaf(hs[i], whi[i], vbi[i]));
            float zf = fmaf(xv, wxf[i], fmaf(hs[i], whf[i], vbf[i]));
            float zc = fmaf(xv, wxc[i], fmaf(hs[i], whc[i], vbc[i]));
            float zo = fmaf(xv, wxo[i], fmaf(hs[i], who[i], vbo[i]));
            if (i > 0) {   // layer-skip from h of layer below (this timestep)
                zi = fmaf(hbelow, wsi[i - 1], zi);
                zf = fmaf(hbelow, wsf[i - 1], zf);
                zc = fmaf(hbelow, wsc[i - 1], zc);
                zo = fmaf(hbelow, wso[i - 1], zo);
            }
            const float ig = sig_p(zi);
            const float fg = sig_p(zf);
            const float og = sig_p(zo);
            const float cc = tanh_p(zc);            // zc already 2*log2e-scaled
            const float cn = fmaf(fg, cs[i], ig * cc);
            const float hn = og * tanh_p(cn * L2E2);
            cs[i] = cn;
            hs[i] = hn;
            hbelow = hn;
            // ys layout: (T, 2, NL, H, H) -- c plane then h plane
            __builtin_nontemporal_store(cn, outp + (size_t)i * HH);
            __builtin_nontemporal_store(hn, outp + (size_t)(NL + i) * HH);
        }
        xv = xnext;
        outp += (size_t)(2 * NL) * HH;
    }
}

extern "C" void kernel_launch(void* const* d_in, const int* in_sizes, int n_in,
                              void* d_out, int out_size, void* d_ws, size_t ws_size,
                              hipStream_t stream) {
    const float* x    = (const float*)d_in[0];
    const float* Wxi  = (const float*)d_in[1];
    const float* Wxf  = (const float*)d_in[2];
    const float* Wxc  = (const float*)d_in[3];
    const float* Wxo  = (const float*)d_in[4];
    const float* Whi  = (const float*)d_in[5];
    const float* Whf  = (const float*)d_in[6];
    const float* Whc  = (const float*)d_in[7];
    const float* Who  = (const float*)d_in[8];
    const float* Whsi = (const float*)d_in[9];
    const float* Whsf = (const float*)d_in[10];
    const float* Whsc = (const float*)d_in[11];
    const float* Whso = (const float*)d_in[12];
    const float* bi   = (const float*)d_in[13];
    const float* bf   = (const float*)d_in[14];
    const float* bc   = (const float*)d_in[15];
    const float* bo   = (const float*)d_in[16];
    float* out = (float*)d_out;

    dim3 grid(HH / 256), block(256);
    slstm_kernel<<<grid, block, 0, stream>>>(x, Wxi, Wxf, Wxc, Wxo,
                                             Whi, Whf, Whc, Who,
                                             Whsi, Whsf, Whsc, Whso,
                                             bi, bf, bc, bo, out);
}